// Round 9
// baseline (589.821 us; speedup 1.0000x reference)
//
#include <hip/hip_runtime.h>
#include <hip/hip_bf16.h>

typedef __attribute__((ext_vector_type(8))) short short8;
typedef __attribute__((ext_vector_type(4))) float floatx4;

#define NB 64
#define NS 512
#define ND 768
#define NH 12

__device__ __forceinline__ float bf2f(unsigned short u) {
  union { unsigned int i; float f; } v; v.i = ((unsigned int)u) << 16; return v.f;
}
__device__ __forceinline__ unsigned short f2bf(float f) {
  union { float f; unsigned int i; } v; v.f = f;
  unsigned int i = v.i;
  unsigned int r = i + 0x7fffu + ((i >> 16) & 1u);
  return (unsigned short)(r >> 16);
}
__device__ __forceinline__ short8 cvt8(const float4 a, const float4 b) {
  short8 r;
  r[0] = (short)f2bf(a.x); r[1] = (short)f2bf(a.y);
  r[2] = (short)f2bf(a.z); r[3] = (short)f2bf(a.w);
  r[4] = (short)f2bf(b.x); r[5] = (short)f2bf(b.y);
  r[6] = (short)f2bf(b.z); r[7] = (short)f2bf(b.w);
  return r;
}

// async global->LDS, 16B per lane. LDS dest is wave-uniform base + lane*16.
__device__ __forceinline__ void gload_lds16(const unsigned short* g, unsigned short* l) {
  __builtin_amdgcn_global_load_lds(
      (const __attribute__((address_space(1))) unsigned int*)g,
      (__attribute__((address_space(3))) unsigned int*)l, 16, 0, 0);
}

#define WAITV(n) asm volatile("s_waitcnt vmcnt(" #n ")" ::: "memory")
#define PH_BAR() __builtin_amdgcn_s_barrier()
#define CFENCE() asm volatile("" ::: "memory")
#define PH_LGKM0()                                        \
  {                                                       \
    asm volatile("s_waitcnt lgkmcnt(0)" ::: "memory");    \
    __builtin_amdgcn_sched_barrier(0);                    \
  }

// ------- prep: transpose+cvt both weight matrices (x conversion now fused in GEMM) ----
// blocks [0,1728): w_qkv^T tiles (72 x 24); [1728,2304): w_o^T tiles (24 x 24).
__global__ void prep_k(const float* __restrict__ w_qkv, unsigned short* __restrict__ wqkvT,
                       const float* __restrict__ w_o, unsigned short* __restrict__ woT) {
  __shared__ unsigned short tile[32][33];
  int id = blockIdx.x;
  int tx = threadIdx.x, ty = threadIdx.y;
  const float* in;
  unsigned short* out;
  int R, C, bx, by;
  if (id < 1728) { in = w_qkv; out = wqkvT; R = 768; C = 2304; bx = id % 72; by = id / 72; }
  else { int i2 = id - 1728; in = w_o; out = woT; R = 768; C = 768; bx = i2 % 24; by = i2 / 24; }
  int c0 = bx * 32, r0 = by * 32;
#pragma unroll
  for (int i = 0; i < 32; i += 8)
    tile[ty + i][tx] = f2bf(in[(r0 + ty + i) * C + c0 + tx]);
  __syncthreads();
#pragma unroll
  for (int i = 0; i < 32; i += 8) out[(c0 + ty + i) * R + r0 + tx] = tile[tx][ty + i];
}

// ---------------- GEMM: C = A(MxK) * Bt(NxK bf16)^T + bias(fp32) ----------------
// 128x128 tile, BK=32, 4 waves (2Mx2N), 2-slot LDS double-buffer, counted vmcnt
// (never 0 mid-loop), raw-barrier 2-phase loop, XOR chunk swizzle, XCD block swizzle.
// MODE 0: A bf16 via gload_lds, fp32 store, 4 blocks/CU.
// MODE 1: A = fp32 x, converted in-staging (reg-stage + ds_write, double reg buffer);
//         bf16 scatter Q/K (B,H,S,64) with fused RoPE (Q pre-scaled 0.125), Vt (B,H,64,S).
template <int MODE>
__global__ __launch_bounds__(256, MODE == 0 ? 4 : 3) void gemm_k(
    const unsigned short* __restrict__ A, const unsigned short* __restrict__ Bt,
    const float* __restrict__ Axf, const float* __restrict__ bias,
    float* __restrict__ out, unsigned short* __restrict__ Qg,
    unsigned short* __restrict__ Kg, unsigned short* __restrict__ Vtg,
    int M, int N, int K) {
  __shared__ unsigned short As[2][128 * 32];  // 2 slots x 8 KB
  __shared__ unsigned short Bs[2][128 * 32];

  // XCD-aware swizzle (nwg % 8 == 0: QKV 4608, proj 1536)
  int nbx = N >> 7;
  int nwg = (M >> 7) * nbx;
  int id = blockIdx.x;
  int q8 = nwg >> 3;
  int wg = (id & 7) * q8 + (id >> 3);
  int bx = wg % nbx, by = wg / nbx;
  int n0 = bx * 128, m0 = by * 128;

  int t = threadIdx.x;
  int w = t >> 6, lane = t & 63;
  int wm = (w >> 1) * 64, wn = (w & 1) * 64;  // wave owns 64x64 of C
  int lr = lane & 15, lq = lane >> 4;

  // staging geometry: thread t covers row t>>2; phys chunk (t&3)^((t>>3)&3) holds
  // global chunk (t&3) (ds_write path) / source pre-swizzle (gload_lds path).
  int srow = t >> 2;
  int sch = ((t & 3) ^ ((t >> 3) & 3)) * 8;
  const unsigned short* Bg = Bt + (size_t)(n0 + srow) * K + sch;
  const size_t rowskip = (size_t)64 * K;
  int ldso = w * 512;

  // frag-read chunk offset (same involution)
  int cs = (lq ^ ((lr >> 1) & 3)) * 8;
  int rA = (wm + lr) * 32 + cs;
  int rB = (wn + lr) * 32 + cs;

  floatx4 acc[4][4];
#pragma unroll
  for (int i = 0; i < 4; i++)
#pragma unroll
    for (int j = 0; j < 4; j++) acc[i][j] = (floatx4){0.f, 0.f, 0.f, 0.f};

  const int NKT = K >> 5;  // 24 for K=768

  if constexpr (MODE == 0) {
    const unsigned short* Ag = A + (size_t)(m0 + srow) * K + sch;
#define STAGE(kt_)                                                \
  {                                                               \
    int s_ = (kt_) & 1;                                           \
    gload_lds16(Ag + (kt_) * 32, &As[s_][ldso]);                  \
    gload_lds16(Ag + rowskip + (kt_) * 32, &As[s_][2048 + ldso]); \
    gload_lds16(Bg + (kt_) * 32, &Bs[s_][ldso]);                  \
    gload_lds16(Bg + rowskip + (kt_) * 32, &Bs[s_][2048 + ldso]); \
  }
    STAGE(0);
    for (int kt = 0; kt < NKT; ++kt) {
      int cur = kt & 1;
      if (kt + 1 < NKT) {
        STAGE(kt + 1);
        WAITV(4);
      } else {
        WAITV(0);
      }
      PH_BAR();
      CFENCE();
      short8 af[4], bfr[4];
#pragma unroll
      for (int mt = 0; mt < 4; mt++) af[mt] = *(const short8*)&As[cur][rA + mt * 512];
#pragma unroll
      for (int nt = 0; nt < 4; nt++) bfr[nt] = *(const short8*)&Bs[cur][rB + nt * 512];
#pragma unroll
      for (int mt = 0; mt < 4; mt++)
#pragma unroll
        for (int nt = 0; nt < 4; nt++)
          acc[mt][nt] =
              __builtin_amdgcn_mfma_f32_16x16x32_bf16(af[mt], bfr[nt], acc[mt][nt], 0, 0, 0);
      CFENCE();
      PH_BAR();
    }
#undef STAGE
  } else {
    // fused fp32->bf16 A staging. x row stride = 768 floats; +49152 = 64 rows.
    const float* gAx = Axf + ((size_t)m0 + srow) * 768 + (t & 3) * 8;
    int wrlo = srow * 32 + sch;   // ds_write addr: phys chunk carries the involution
    int wrhi = wrlo + 2048;
    float4 rg0[4], rg1[4];
#define LOADA(kt_, RG)                                                   \
  {                                                                      \
    const float* p_ = gAx + (kt_) * 32;                                  \
    RG[0] = *(const float4*)p_;                                          \
    RG[1] = *(const float4*)(p_ + 4);                                    \
    RG[2] = *(const float4*)(p_ + 49152);                                \
    RG[3] = *(const float4*)(p_ + 49152 + 4);                            \
  }
    // steady-state outstanding before WAITV: [A(kt)x4, B(kt)x2, A(kt+1)x4, B(kt+1)x2]
    // -> WAITV(6) certifies tile kt exactly; WAITV(0) only at the final iter.
#define ITER1(kt_, RG)                                                        \
  {                                                                           \
    int s_ = (kt_) & 1;                                                       \
    if ((kt_) + 1 < NKT) {                                                    \
      gload_lds16(Bg + ((kt_) + 1) * 32, &Bs[((kt_) + 1) & 1][ldso]);         \
      gload_lds16(Bg + rowskip + ((kt_) + 1) * 32,                            \
                  &Bs[((kt_) + 1) & 1][2048 + ldso]);                         \
    }                                                                         \
    if ((kt_) == NKT - 1) { WAITV(0); } else { WAITV(6); }                    \
    CFENCE();                                                                 \
    short8 w0_ = cvt8(RG[0], RG[1]);                                          \
    short8 w1_ = cvt8(RG[2], RG[3]);                                          \
    *(short8*)&As[s_][wrlo] = w0_;                                            \
    *(short8*)&As[s_][wrhi] = w1_;                                            \
    if ((kt_) + 2 < NKT) LOADA((kt_) + 2, RG);                                \
    PH_LGKM0();                                                               \
    PH_BAR();                                                                 \
    short8 af[4], bfr[4];                                                     \
    _Pragma("unroll") for (int mt = 0; mt < 4; mt++)                          \
        af[mt] = *(const short8*)&As[s_][rA + mt * 512];                      \
    _Pragma("unroll") for (int nt = 0; nt < 4; nt++)                          \
        bfr[nt] = *(const short8*)&Bs[s_][rB + nt * 512];                     \
    _Pragma("unroll") for (int mt = 0; mt < 4; mt++)                          \
        _Pragma("unroll") for (int nt = 0; nt < 4; nt++)                      \
            acc[mt][nt] = __builtin_amdgcn_mfma_f32_16x16x32_bf16(            \
                af[mt], bfr[nt], acc[mt][nt], 0, 0, 0);                       \
    CFENCE();                                                                 \
    PH_BAR();                                                                 \
  }
    LOADA(0, rg0);
    gload_lds16(Bg, &Bs[0][ldso]);
    gload_lds16(Bg + rowskip, &Bs[0][2048 + ldso]);
    LOADA(1, rg1);
    for (int kt2 = 0; kt2 < NKT; kt2 += 2) {
      ITER1(kt2, rg0);
      ITER1(kt2 + 1, rg1);
    }
#undef ITER1
#undef LOADA
  }

  // ---------------- epilogue ----------------
  float bv[4];
#pragma unroll
  for (int nt = 0; nt < 4; nt++) bv[nt] = bias[n0 + wn + nt * 16 + lr];

  int part = 0, h = 0;
  float ivf0 = 0.f, ivf1 = 0.f, qs = 1.f;
  if (MODE == 1) {
    int nbase = n0 + wn;            // wave-uniform, 64-aligned => one head, one part
    part = nbase / ND;
    h = (nbase - part * ND) >> 6;
    ivf0 = __expf(-(float)lr * 0.28782313662425572f);         // invfreq(d=lr)
    ivf1 = __expf(-(float)(16 + lr) * 0.28782313662425572f);  // invfreq(d=16+lr)
    if (part == 0) qs = 0.125f;     // fold 1/sqrt(dk) into Q
  }

#pragma unroll
  for (int mt = 0; mt < 4; mt++) {
#pragma unroll
    for (int r = 0; r < 4; r++) {
      int m = m0 + wm + mt * 16 + lq * 4 + r;  // C/D: row=(lane>>4)*4+reg, col=lane&15
      float fo[4];
#pragma unroll
      for (int nt = 0; nt < 4; nt++) fo[nt] = acc[mt][nt][r] + bv[nt];
      if (MODE == 0) {
#pragma unroll
        for (int nt = 0; nt < 4; nt++)
          out[(size_t)m * N + (n0 + wn + nt * 16 + lr)] = fo[nt];
      } else {
        int b = m >> 9, s = m & 511;
        int bh = b * NH + h;
        if (part == 2) {
#pragma unroll
          for (int nt = 0; nt < 4; nt++)
            Vtg[((size_t)bh * 64 + nt * 16 + lr) * NS + s] = f2bf(fo[nt]);
        } else {
          // fused RoPE: head cols c = nt*16+lr; outputs (d, d+32) need inputs (2d, 2d+1).
          unsigned short* dst = (part ? Kg : Qg) + ((size_t)bh * NS + s) * 64;
          int sl0 = (lq << 4) | ((2 * lr) & 15);
          int sl1 = (lq << 4) | ((2 * lr + 1) & 15);
          float a_l = __shfl(fo[0], sl0), a_h = __shfl(fo[1], sl0);
          float b_l = __shfl(fo[0], sl1), b_h = __shfl(fo[1], sl1);
          float c_l = __shfl(fo[2], sl0), c_h = __shfl(fo[3], sl0);
          float d_l = __shfl(fo[2], sl1), d_h = __shfl(fo[3], sl1);
          bool lo = lr < 8;
          float Av = lo ? a_l : a_h, Bv = lo ? b_l : b_h;   // in(2lr), in(2lr+1)
          float Cv = lo ? c_l : c_h, Dv = lo ? d_l : d_h;   // in(32+2lr), in(33+2lr)
          float fs = (float)s;
          float sn0, cs0, sn1, cs1;
          __sincosf(fs * ivf0, &sn0, &cs0);
          __sincosf(fs * ivf1, &sn1, &cs1);
          dst[lr]      = f2bf((Av * cs0 - Bv * sn0) * qs);  // d = lr
          dst[16 + lr] = f2bf((Cv * cs1 - Dv * sn1) * qs);  // d = 16+lr
          dst[32 + lr] = f2bf((Av * sn0 + Bv * cs0) * qs);  // d+32
          dst[48 + lr] = f2bf((Cv * sn1 + Dv * cs1) * qs);  // d+32
        }
      }
    }
  }
}

// ---------------- flash attention: 1 WG = (b,h) x 128 q-rows, 8 waves ----------------
// Grid = (bh, qt=4): bh-major => all blocks of one bh on the same XCD (K/V L2-resident).
// K/V double-buffered via global_load_lds, XOR chunk involution, counted vmcnt(2).
// Q is pre-scaled by 0.125 in the QKV epilogue, so scores need no scaling here.
__global__ __launch_bounds__(512) void attn_k(
    const unsigned short* __restrict__ Qg, const unsigned short* __restrict__ Kg,
    const unsigned short* __restrict__ Vtg, unsigned short* __restrict__ ctx) {
  __shared__ unsigned short Ks[2][4096];   // 64 rows x 64 cols bf16, chunk-swizzled
  __shared__ unsigned short Vs[2][4096];   // V^T: 64 d-rows x 64 s-cols, chunk-swizzled
  __shared__ unsigned short Ps[8][16 * 72];
  int bh = blockIdx.x, qt = blockIdx.y;
  int t = threadIdx.x, w = t >> 6, lane = t & 63;
  int lr = lane & 15, lq = lane >> 4;
  int q0 = qt * 128 + w * 16;
  const unsigned short* Qb = Qg + (bh * NS + q0) * 64;
  short8 qf0 = *(const short8*)&Qb[lr * 64 + lq * 8];
  short8 qf1 = *(const short8*)&Qb[lr * 64 + 32 + lq * 8];
  floatx4 o[4];
#pragma unroll
  for (int ft = 0; ft < 4; ft++) o[ft] = (floatx4){0.f, 0.f, 0.f, 0.f};
  float m_[4] = {-1e30f, -1e30f, -1e30f, -1e30f};
  float l_[4] = {0.f, 0.f, 0.f, 0.f};

  int srow = t >> 3;
  int sch = ((t & 7) ^ (srow & 7)) * 8;
  const unsigned short* gK = Kg + bh * NS * 64 + srow * 64 + sch;   // + kt*4096
  const unsigned short* gV = Vtg + bh * 64 * NS + srow * NS + sch;  // + kt*64
  int c0 = (lq ^ (lr & 7)) * 8;
  int c1 = ((4 + lq) ^ (lr & 7)) * 8;

  gload_lds16(gK, &Ks[0][w * 512]);
  gload_lds16(gV, &Vs[0][w * 512]);

  for (int kt = 0; kt < 8; kt++) {
    int cur = kt & 1;
    PH_BAR();  // all waves done reading buf[cur^1] -> safe to overwrite
    if (kt < 7) {
      gload_lds16(gK + (kt + 1) * 4096, &Ks[cur ^ 1][w * 512]);
      gload_lds16(gV + (kt + 1) * 64, &Vs[cur ^ 1][w * 512]);
      WAITV(2);  // cur's 2 loads landed; next's 2 stay in flight
    } else {
      WAITV(0);
    }
    PH_BAR();  // all waves certified buf[cur]

    floatx4 sf[4];
#pragma unroll
    for (int nt = 0; nt < 4; nt++) sf[nt] = (floatx4){0.f, 0.f, 0.f, 0.f};
#pragma unroll
    for (int nt = 0; nt < 4; nt++) {
      short8 k0 = *(const short8*)&Ks[cur][(nt * 16 + lr) * 64 + c0];
      short8 k1 = *(const short8*)&Ks[cur][(nt * 16 + lr) * 64 + c1];
      sf[nt] = __builtin_amdgcn_mfma_f32_16x16x32_bf16(qf0, k0, sf[nt], 0, 0, 0);
      sf[nt] = __builtin_amdgcn_mfma_f32_16x16x32_bf16(qf1, k1, sf[nt], 0, 0, 0);
    }
    float alpha[4];
#pragma unroll
    for (int r = 0; r < 4; r++) {
      float v = fmaxf(fmaxf(sf[0][r], sf[1][r]), fmaxf(sf[2][r], sf[3][r]));
      v = fmaxf(v, __shfl_xor(v, 1));
      v = fmaxf(v, __shfl_xor(v, 2));
      v = fmaxf(v, __shfl_xor(v, 4));
      v = fmaxf(v, __shfl_xor(v, 8));
      float mn = fmaxf(m_[r], v);
      alpha[r] = __expf(m_[r] - mn);
      m_[r] = mn;
    }
    float rsum[4] = {0.f, 0.f, 0.f, 0.f};
#pragma unroll
    for (int nt = 0; nt < 4; nt++)
#pragma unroll
      for (int r = 0; r < 4; r++) {
        float pv = __expf(sf[nt][r] - m_[r]);
        rsum[r] += pv;
        Ps[w][(lq * 4 + r) * 72 + nt * 16 + lr] = f2bf(pv);
      }
#pragma unroll
    for (int r = 0; r < 4; r++) {
      float v = rsum[r];
      v += __shfl_xor(v, 1);
      v += __shfl_xor(v, 2);
      v += __shfl_xor(v, 4);
      v += __shfl_xor(v, 8);
      l_[r] = l_[r] * alpha[r] + v;
    }
#pragma unroll
    for (int ft = 0; ft < 4; ft++)
#pragma unroll
      for (int r = 0; r < 4; r++) o[ft][r] *= alpha[r];
    // per-wave LDS RAW fence: Ps writes above -> Ps reads below (same wave, diff lanes)
    PH_LGKM0();
#pragma unroll
    for (int ks = 0; ks < 2; ks++) {
      short8 pf = *(const short8*)&Ps[w][lr * 72 + ks * 32 + lq * 8];
      int vco = ks ? c1 : c0;  // logical chunk ks*4+lq, swizzled
#pragma unroll
      for (int ft = 0; ft < 4; ft++) {
        short8 vf = *(const short8*)&Vs[cur][(ft * 16 + lr) * 64 + vco];
        o[ft] = __builtin_amdgcn_mfma_f32_16x16x32_bf16(pf, vf, o[ft], 0, 0, 0);
      }
    }
  }
  int b = bh / NH, h = bh - (bh / NH) * NH;
#pragma unroll
  for (int r = 0; r < 4; r++) {
    float inv = 1.f / l_[r];
#pragma unroll
    for (int ft = 0; ft < 4; ft++)
      ctx[(b * NS + q0 + lq * 4 + r) * ND + h * 64 + ft * 16 + lr] = f2bf(o[ft][r] * inv);
  }
}

extern "C" void kernel_launch(void* const* d_in, const int* in_sizes, int n_in,
                              void* d_out, int out_size, void* d_ws, size_t ws_size,
                              hipStream_t stream) {
  const float* x     = (const float*)d_in[0];   // fp32 (confirmed: bf16 read -> NaN)
  const float* w_qkv = (const float*)d_in[1];   // (768, 2304) fp32
  const float* b_qkv = (const float*)d_in[2];
  const float* w_o   = (const float*)d_in[3];   // (768, 768) fp32
  const float* b_o   = (const float*)d_in[4];
  float* out = (float*)d_out;                   // fp32: reference output dtype

  char* ws = (char*)d_ws;
  unsigned short* xb    = (unsigned short*)(ws);              // ctx buffer (x read direct now)
  unsigned short* wqkvT = (unsigned short*)(ws + 50331648);   // 2304x768 bf16
  unsigned short* woT   = (unsigned short*)(ws + 53870592);   // 768x768 bf16
  unsigned short* Qg    = (unsigned short*)(ws + 55050240);   // (B,H,S,64) bf16, roped+scaled
  unsigned short* Kg    = (unsigned short*)(ws + 105381888);  // roped
  unsigned short* Vtg   = (unsigned short*)(ws + 155713536);
  unsigned short* ctx   = xb;

  prep_k<<<dim3(2304), dim3(32, 8), 0, stream>>>(w_qkv, wqkvT, w_o, woT);
  gemm_k<1><<<dim3(4608), dim3(256), 0, stream>>>(
      nullptr, wqkvT, x, b_qkv, nullptr, Qg, Kg, Vtg, 32768, 2304, 768);
  attn_k<<<dim3(NB * NH, NS / 128), dim3(512), 0, stream>>>(Qg, Kg, Vtg, ctx);
  gemm_k<0><<<dim3(1536), dim3(256), 0, stream>>>(
      ctx, woT, nullptr, b_o, out, nullptr, nullptr, nullptr, 32768, 768, 768);
}